// Round 11
// baseline (323.023 us; speedup 1.0000x reference)
//
#include <hip/hip_runtime.h>

#define ROWS  16
#define BLOCK 512
#define PAD   620   // 616 padded; 2480B row, 16B-aligned

typedef float v2f __attribute__((ext_vector_type(2)));

__device__ inline unsigned pack4_fp8(float a, float b, float c, float d) {
    int t = __builtin_amdgcn_cvt_pk_fp8_f32(a, b, 0, false);   // bytes [1:0]
    t     = __builtin_amdgcn_cvt_pk_fp8_f32(c, d, t, true);    // bytes [3:2]
    return (unsigned)t;
}

// ---------------- kernel 1: quantize BOTH tables f32[*,172] -> fp8 rows (176B, 11x uint4) ----------------
// items: node 200000*11, then edge 500000*11
__global__ __launch_bounds__(256) void quant_all(
    const float* __restrict__ nodef,   // [200000,172]
    const float* __restrict__ edgef,   // [500000,172]
    uint4*       __restrict__ nodeQ,   // [200000,11]
    uint4*       __restrict__ edgeQ)   // [500000,11]
{
    const int NODE_ITEMS = 200000 * 11;
    const int TOT_ITEMS  = NODE_ITEMS + 500000 * 11;
    int i = blockIdx.x * 256 + threadIdx.x;
    if (i >= TOT_ITEMS) return;
    const float* src; uint4* dst; int row, c;
    if (i < NODE_ITEMS) { row = i / 11; c = i - row * 11; src = nodef; dst = nodeQ; }
    else { int j = i - NODE_ITEMS; row = j / 11; c = j - row * 11; src = edgef; dst = edgeQ; }

    const float4* s = (const float4*)(src + (size_t)row * 172);
    float v[16];
    if (c < 10) {
        #pragma unroll
        for (int j = 0; j < 4; ++j) {
            float4 f = s[4 * c + j];
            v[4*j+0] = f.x; v[4*j+1] = f.y; v[4*j+2] = f.z; v[4*j+3] = f.w;
        }
    } else {
        #pragma unroll
        for (int j = 0; j < 3; ++j) {
            float4 f = s[40 + j];
            v[4*j+0] = f.x; v[4*j+1] = f.y; v[4*j+2] = f.z; v[4*j+3] = f.w;
        }
        v[12] = v[13] = v[14] = v[15] = 0.f;
    }
    uint4 o;
    o.x = pack4_fp8(v[0],  v[1],  v[2],  v[3]);
    o.y = pack4_fp8(v[4],  v[5],  v[6],  v[7]);
    o.z = pack4_fp8(v[8],  v[9],  v[10], v[11]);
    o.w = pack4_fp8(v[12], v[13], v[14], v[15]);
    dst[(size_t)row * 11 + c] = o;
}

// ---------------- kernel 2: fused gather(fp8) + cur + time + GEMM + ReLU ----------------
__global__ __launch_bounds__(BLOCK) void spe_fused_q(
    const float* __restrict__ nodef,
    const uint4* __restrict__ nodeQ,   // [200000,11] fp8
    const uint4* __restrict__ edgeQ,   // [500000,11] fp8
    const int*   __restrict__ src_ids,
    const int*   __restrict__ dst_ids,
    const float* __restrict__ itimes,
    const int*   __restrict__ s_nbr,
    const int*   __restrict__ s_eid,
    const float* __restrict__ s_t,
    const int*   __restrict__ d_nbr,
    const int*   __restrict__ d_eid,
    const float* __restrict__ d_t,
    const float* __restrict__ tw,
    const float* __restrict__ tb,
    const float* __restrict__ W,       // [616,172]
    const float* __restrict__ bout,    // [172]
    float*       __restrict__ out)     // [3,8192,172]
{
    __shared__ float inp[ROWS * PAD];
    __shared__ int   nid_s[ROWS * 32];
    __shared__ int   eid_s[ROWS * 32];
    __shared__ float dtm[ROWS * 32];
    __shared__ float msk[ROWS * 32];
    __shared__ int   curoff[ROWS];
    __shared__ float twl[100], tbl[100];

    const int tid     = threadIdx.x;
    const int side    = blockIdx.x >> 9;           // 512 blocks per side
    const int rowbase = (blockIdx.x & 511) * ROWS;

    const int*   nbr  = side ? d_nbr : s_nbr;
    const int*   eidp = side ? d_eid : s_eid;
    const float* ntp  = side ? d_t   : s_t;
    const int*   nids = side ? dst_ids : src_ids;

    // ---- stage ids / dt / mask (one item per thread: 16*32 == 512) ----
    {
        int i    = tid;
        int g    = rowbase * 32 + i;
        int nid  = nbr[g];
        nid_s[i] = nid;
        eid_s[i] = eidp[g];
        dtm[i]   = itimes[rowbase + (i >> 5)] - ntp[g];
        msk[i]   = (nid == 0) ? 0.f : 1.f;
    }
    if (tid < ROWS) curoff[tid] = nids[rowbase + tid] * 172;
    if (tid < 100) { twl[tid] = tw[tid]; tbl[tid] = tb[tid]; }
    __syncthreads();

    // ---- cur node copy (f32): inp[r][0:172] ----
    for (int i = tid; i < ROWS * 43; i += BLOCK) {
        int r = i / 43, c = i - r * 43;
        *(float4*)&inp[r * PAD + 4 * c] =
            *(const float4*)&nodef[curoff[r] + 4 * c];
    }

    // ---- fp8 gather means: items = (r, cc); cc<11 node chunk, cc>=11 edge chunk ----
    for (int i = tid; i < ROWS * 22; i += BLOCK) {
        int r = i / 22, cc = i - r * 22;
        const bool is_edge = cc >= 11;
        const int  c  = is_edge ? cc - 11 : cc;
        const int  rb = r * 32;
        const uint4* Q    = is_edge ? edgeQ : nodeQ;
        const int*   ids  = is_edge ? eid_s : nid_s;

        float acc[16];
        #pragma unroll
        for (int k = 0; k < 16; ++k) acc[k] = 0.f;

        #pragma unroll
        for (int s0 = 0; s0 < 32; s0 += 8) {
            uint4 v[8];
            #pragma unroll
            for (int u = 0; u < 8; ++u)
                v[u] = Q[(size_t)ids[rb + s0 + u] * 11 + c];
            #pragma unroll
            for (int u = 0; u < 8; ++u) {
                unsigned w[4] = {v[u].x, v[u].y, v[u].z, v[u].w};
                #pragma unroll
                for (int q = 0; q < 4; ++q) {
                    v2f lo = __builtin_amdgcn_cvt_pk_f32_fp8((int)w[q], false);
                    v2f hi = __builtin_amdgcn_cvt_pk_f32_fp8((int)w[q], true);
                    acc[4*q+0] += lo.x; acc[4*q+1] += lo.y;
                    acc[4*q+2] += hi.x; acc[4*q+3] += hi.y;
                }
            }
        }

        // write mean into inp: node section base 172, edge base 344; chunk c covers dims 16c..
        float* dstp = &inp[r * PAD + (is_edge ? 344 : 172) + 16 * c];
        int nf4 = (c == 10) ? 3 : 4;   // last chunk has only 12 valid dims
        #pragma unroll
        for (int j = 0; j < 4; ++j) {
            if (j < nf4) {
                float4 o = { acc[4*j+0] * (1.f/32.f), acc[4*j+1] * (1.f/32.f),
                             acc[4*j+2] * (1.f/32.f), acc[4*j+3] * (1.f/32.f) };
                *(float4*)(dstp + 4 * j) = o;
            }
        }
    }

    // ---- time encoding: inp[r][516+j] ----
    for (int i = tid; i < ROWS * 100; i += BLOCK) {
        int r = i / 100, j = i - r * 100;
        const int rb = r * 32;
        float w = twl[j], b = tbl[j];
        float acc = 0.f;
        #pragma unroll
        for (int s = 0; s < 32; ++s)
            acc += msk[rb + s] * __cosf(dtm[rb + s] * w + b);
        inp[r * PAD + 516 + j] = acc * (1.f / 32.f);
    }
    __syncthreads();

    // ---- GEMM: out[16,172] = relu(inp[16,616] @ W[616,172] + b) ----
    // 344 threads = 8 row-tiles x 43 col-tiles, each thread 2 rows x 4 cols
    if (tid < 344) {
        const int ct = tid % 43, rt = tid / 43;
        const int j0 = ct * 4, r0 = rt * 2;
        float acc[2][4] = {};
        float a[2][4];
        for (int k = 0; k < 616; k += 4) {
            #pragma unroll
            for (int ri = 0; ri < 2; ++ri)
                *(float4*)&a[ri][0] = *(const float4*)&inp[(r0 + ri) * PAD + k];
            #pragma unroll
            for (int kk = 0; kk < 4; ++kk) {
                float4 wv = *(const float4*)&W[(k + kk) * 172 + j0];
                #pragma unroll
                for (int ri = 0; ri < 2; ++ri) {
                    acc[ri][0] += a[ri][kk] * wv.x;
                    acc[ri][1] += a[ri][kk] * wv.y;
                    acc[ri][2] += a[ri][kk] * wv.z;
                    acc[ri][3] += a[ri][kk] * wv.w;
                }
            }
        }
        float4 bias = *(const float4*)&bout[j0];
        #pragma unroll
        for (int ri = 0; ri < 2; ++ri) {
            int row = rowbase + r0 + ri;
            float4 v;
            v.x = fmaxf(acc[ri][0] + bias.x, 0.f);
            v.y = fmaxf(acc[ri][1] + bias.y, 0.f);
            v.z = fmaxf(acc[ri][2] + bias.z, 0.f);
            v.w = fmaxf(acc[ri][3] + bias.w, 0.f);
            *(float4*)&out[(size_t)(side * 8192 + row) * 172 + j0] = v;
        }
    }

    // ---- dummy third output = zeros (side-0 blocks) ----
    if (side == 0) {
        const float4 z = {0.f, 0.f, 0.f, 0.f};
        for (int i = tid; i < ROWS * 43; i += BLOCK) {
            int r = i / 43, c = i - r * 43;
            *(float4*)&out[(size_t)(2 * 8192 + rowbase + r) * 172 + 4 * c] = z;
        }
    }
}

extern "C" void kernel_launch(void* const* d_in, const int* in_sizes, int n_in,
                              void* d_out, int out_size, void* d_ws, size_t ws_size,
                              hipStream_t stream) {
    const float* nodef   = (const float*)d_in[0];
    const float* edgef   = (const float*)d_in[1];
    const int*   src_ids = (const int*)  d_in[2];
    const int*   dst_ids = (const int*)  d_in[3];
    const float* itimes  = (const float*)d_in[4];
    const int*   s_nbr   = (const int*)  d_in[5];
    const int*   s_eid   = (const int*)  d_in[6];
    const float* s_t     = (const float*)d_in[7];
    const int*   d_nbr   = (const int*)  d_in[8];
    const int*   d_eid   = (const int*)  d_in[9];
    const float* d_t     = (const float*)d_in[10];
    const float* tw      = (const float*)d_in[11];
    const float* tb      = (const float*)d_in[12];
    const float* W       = (const float*)d_in[13];
    const float* bout    = (const float*)d_in[14];
    float* out = (float*)d_out;

    // ws: nodeQ fp8[200000,176B] = 35.2MB @0 ; edgeQ fp8[500000,176B] = 88MB @48MB
    char*  ws    = (char*)d_ws;
    uint4* nodeQ = (uint4*)ws;
    uint4* edgeQ = (uint4*)(ws + (size_t)48 * 1024 * 1024);

    // quantize both tables (one streaming kernel): (200000+500000)*11 items
    quant_all<<<30079, 256, 0, stream>>>(nodef, edgef, nodeQ, edgeQ);

    // fused gather(fp8, L3-resident) + cur(f32) + time + GEMM
    spe_fused_q<<<1024, BLOCK, 0, stream>>>(
        nodef, nodeQ, edgeQ, src_ids, dst_ids, itimes,
        s_nbr, s_eid, s_t, d_nbr, d_eid, d_t,
        tw, tb, W, bout, out);
}

// Round 12
// 284.296 us; speedup vs baseline: 1.1362x; 1.1362x over previous
//
#include <hip/hip_runtime.h>

#define ROWS  8
#define BLOCK 256
#define PAD   620   // 616 padded; 2480B row, 16B-aligned

typedef float v2f __attribute__((ext_vector_type(2)));

__device__ inline unsigned pack4_fp8(float a, float b, float c, float d) {
    int t = __builtin_amdgcn_cvt_pk_fp8_f32(a, b, 0, false);   // bytes [1:0]
    t     = __builtin_amdgcn_cvt_pk_fp8_f32(c, d, t, true);    // bytes [3:2]
    return (unsigned)t;
}

// ---------------- kernel 1: quantize BOTH tables f32[*,172] -> fp8 rows (176B, 11x uint4) ----------------
__global__ __launch_bounds__(256) void quant_all(
    const float* __restrict__ nodef,   // [200000,172]
    const float* __restrict__ edgef,   // [500000,172]
    uint4*       __restrict__ nodeQ,   // [200000,11]
    uint4*       __restrict__ edgeQ)   // [500000,11]
{
    const int NODE_ITEMS = 200000 * 11;
    const int TOT_ITEMS  = NODE_ITEMS + 500000 * 11;
    int i = blockIdx.x * 256 + threadIdx.x;
    if (i >= TOT_ITEMS) return;
    const float* src; uint4* dst; int row, c;
    if (i < NODE_ITEMS) { row = i / 11; c = i - row * 11; src = nodef; dst = nodeQ; }
    else { int j = i - NODE_ITEMS; row = j / 11; c = j - row * 11; src = edgef; dst = edgeQ; }

    const float4* s = (const float4*)(src + (size_t)row * 172);
    float v[16];
    if (c < 10) {
        #pragma unroll
        for (int j = 0; j < 4; ++j) {
            float4 f = s[4 * c + j];
            v[4*j+0] = f.x; v[4*j+1] = f.y; v[4*j+2] = f.z; v[4*j+3] = f.w;
        }
    } else {
        #pragma unroll
        for (int j = 0; j < 3; ++j) {
            float4 f = s[40 + j];
            v[4*j+0] = f.x; v[4*j+1] = f.y; v[4*j+2] = f.z; v[4*j+3] = f.w;
        }
        v[12] = v[13] = v[14] = v[15] = 0.f;
    }
    uint4 o;
    o.x = pack4_fp8(v[0],  v[1],  v[2],  v[3]);
    o.y = pack4_fp8(v[4],  v[5],  v[6],  v[7]);
    o.z = pack4_fp8(v[8],  v[9],  v[10], v[11]);
    o.w = pack4_fp8(v[12], v[13], v[14], v[15]);
    dst[(size_t)row * 11 + c] = o;
}

// ---------------- kernel 2: fused gather(fp8) + cur + time + GEMM + ReLU ----------------
__global__ __launch_bounds__(BLOCK) void spe_fused_q(
    const float* __restrict__ nodef,
    const uint4* __restrict__ nodeQ,   // [200000,11] fp8
    const uint4* __restrict__ edgeQ,   // [500000,11] fp8
    const int*   __restrict__ src_ids,
    const int*   __restrict__ dst_ids,
    const float* __restrict__ itimes,
    const int*   __restrict__ s_nbr,
    const int*   __restrict__ s_eid,
    const float* __restrict__ s_t,
    const int*   __restrict__ d_nbr,
    const int*   __restrict__ d_eid,
    const float* __restrict__ d_t,
    const float* __restrict__ tw,
    const float* __restrict__ tb,
    const float* __restrict__ W,       // [616,172]
    const float* __restrict__ bout,    // [172]
    float*       __restrict__ out)     // [3,8192,172]
{
    __shared__ float inp[ROWS * PAD];         // ~19.8KB
    __shared__ int   nid_s[ROWS * 32];
    __shared__ int   eid_s[ROWS * 32];
    __shared__ float dtm[ROWS * 32];
    __shared__ float msk[ROWS * 32];
    __shared__ int   curoff[ROWS];
    __shared__ float twl[100], tbl[100];

    const int tid     = threadIdx.x;
    const int side    = blockIdx.x >> 10;            // 1024 blocks per side
    const int rowbase = (blockIdx.x & 1023) * ROWS;

    const int*   nbr  = side ? d_nbr : s_nbr;
    const int*   eidp = side ? d_eid : s_eid;
    const float* ntp  = side ? d_t   : s_t;
    const int*   nids = side ? dst_ids : src_ids;

    // ---- stage ids / dt / mask (ROWS*32 == 256: exactly one item per thread) ----
    {
        int i    = tid;
        int g    = rowbase * 32 + i;
        int nid  = nbr[g];
        nid_s[i] = nid;
        eid_s[i] = eidp[g];
        dtm[i]   = itimes[rowbase + (i >> 5)] - ntp[g];
        msk[i]   = (nid == 0) ? 0.f : 1.f;
    }
    if (tid < ROWS) curoff[tid] = nids[rowbase + tid] * 172;
    if (tid < 100) { twl[tid] = tw[tid]; tbl[tid] = tb[tid]; }
    __syncthreads();

    // ---- fp8 gather means (16-deep batches): items (r, cc), cc<11 node / cc>=11 edge ----
    for (int i = tid; i < ROWS * 22; i += BLOCK) {
        int r = i / 22, cc = i - r * 22;
        const bool is_edge = cc >= 11;
        const int  c  = is_edge ? cc - 11 : cc;
        const int  rb = r * 32;
        const uint4* Q   = is_edge ? edgeQ : nodeQ;
        const int*   ids = is_edge ? eid_s : nid_s;

        float acc[16];
        #pragma unroll
        for (int k = 0; k < 16; ++k) acc[k] = 0.f;

        #pragma unroll
        for (int s0 = 0; s0 < 32; s0 += 16) {
            uint4 v[16];
            #pragma unroll
            for (int u = 0; u < 16; ++u)
                v[u] = Q[(size_t)ids[rb + s0 + u] * 11 + c];
            #pragma unroll
            for (int u = 0; u < 16; ++u) {
                unsigned w[4] = {v[u].x, v[u].y, v[u].z, v[u].w};
                #pragma unroll
                for (int q = 0; q < 4; ++q) {
                    v2f lo = __builtin_amdgcn_cvt_pk_f32_fp8((int)w[q], false);
                    v2f hi = __builtin_amdgcn_cvt_pk_f32_fp8((int)w[q], true);
                    acc[4*q+0] += lo.x; acc[4*q+1] += lo.y;
                    acc[4*q+2] += hi.x; acc[4*q+3] += hi.y;
                }
            }
        }

        float* dstp = &inp[r * PAD + (is_edge ? 344 : 172) + 16 * c];
        int nf4 = (c == 10) ? 3 : 4;   // last chunk: only 12 valid dims
        #pragma unroll
        for (int j = 0; j < 4; ++j) {
            if (j < nf4) {
                float4 o = { acc[4*j+0] * (1.f/32.f), acc[4*j+1] * (1.f/32.f),
                             acc[4*j+2] * (1.f/32.f), acc[4*j+3] * (1.f/32.f) };
                *(float4*)(dstp + 4 * j) = o;
            }
        }
    }

    // ---- cur node copy (f32): inp[r][0:172] ----
    for (int i = tid; i < ROWS * 43; i += BLOCK) {
        int r = i / 43, c = i - r * 43;
        *(float4*)&inp[r * PAD + 4 * c] =
            *(const float4*)&nodef[curoff[r] + 4 * c];
    }

    // ---- time encoding: inp[r][516+j] ----
    for (int i = tid; i < ROWS * 100; i += BLOCK) {
        int r = i / 100, j = i - r * 100;
        const int rb = r * 32;
        float w = twl[j], b = tbl[j];
        float acc = 0.f;
        #pragma unroll
        for (int s = 0; s < 32; ++s)
            acc += msk[rb + s] * __cosf(dtm[rb + s] * w + b);
        inp[r * PAD + 516 + j] = acc * (1.f / 32.f);
    }

    // ---- dummy third output = zeros (side-0 blocks) ----
    if (side == 0) {
        const float4 z = {0.f, 0.f, 0.f, 0.f};
        for (int i = tid; i < ROWS * 43; i += BLOCK) {
            int r = i / 43, c = i - r * 43;
            *(float4*)&out[(size_t)(2 * 8192 + rowbase + r) * 172 + 4 * c] = z;
        }
    }
    __syncthreads();

    // ---- GEMM: out[8,172] = relu(inp[8,616] @ W[616,172] + b) ----
    // 172 threads = 4 row-tiles x 43 col-tiles, each thread 2 rows x 4 cols
    if (tid < 172) {
        const int ct = tid % 43, rt = tid / 43;
        const int j0 = ct * 4, r0 = rt * 2;
        float acc[2][4] = {};
        float a[2][4];
        for (int k = 0; k < 616; k += 4) {
            #pragma unroll
            for (int ri = 0; ri < 2; ++ri)
                *(float4*)&a[ri][0] = *(const float4*)&inp[(r0 + ri) * PAD + k];
            #pragma unroll
            for (int kk = 0; kk < 4; ++kk) {
                float4 wv = *(const float4*)&W[(k + kk) * 172 + j0];
                #pragma unroll
                for (int ri = 0; ri < 2; ++ri) {
                    acc[ri][0] += a[ri][kk] * wv.x;
                    acc[ri][1] += a[ri][kk] * wv.y;
                    acc[ri][2] += a[ri][kk] * wv.z;
                    acc[ri][3] += a[ri][kk] * wv.w;
                }
            }
        }
        float4 bias = *(const float4*)&bout[j0];
        #pragma unroll
        for (int ri = 0; ri < 2; ++ri) {
            int row = rowbase + r0 + ri;
            float4 v;
            v.x = fmaxf(acc[ri][0] + bias.x, 0.f);
            v.y = fmaxf(acc[ri][1] + bias.y, 0.f);
            v.z = fmaxf(acc[ri][2] + bias.z, 0.f);
            v.w = fmaxf(acc[ri][3] + bias.w, 0.f);
            *(float4*)&out[(size_t)(side * 8192 + row) * 172 + j0] = v;
        }
    }
}

extern "C" void kernel_launch(void* const* d_in, const int* in_sizes, int n_in,
                              void* d_out, int out_size, void* d_ws, size_t ws_size,
                              hipStream_t stream) {
    const float* nodef   = (const float*)d_in[0];
    const float* edgef   = (const float*)d_in[1];
    const int*   src_ids = (const int*)  d_in[2];
    const int*   dst_ids = (const int*)  d_in[3];
    const float* itimes  = (const float*)d_in[4];
    const int*   s_nbr   = (const int*)  d_in[5];
    const int*   s_eid   = (const int*)  d_in[6];
    const float* s_t     = (const float*)d_in[7];
    const int*   d_nbr   = (const int*)  d_in[8];
    const int*   d_eid   = (const int*)  d_in[9];
    const float* d_t     = (const float*)d_in[10];
    const float* tw      = (const float*)d_in[11];
    const float* tb      = (const float*)d_in[12];
    const float* W       = (const float*)d_in[13];
    const float* bout    = (const float*)d_in[14];
    float* out = (float*)d_out;

    // ws: nodeQ fp8[200000,176B] = 35.2MB @0 ; edgeQ fp8[500000,176B] = 88MB @48MB
    char*  ws    = (char*)d_ws;
    uint4* nodeQ = (uint4*)ws;
    uint4* edgeQ = (uint4*)(ws + (size_t)48 * 1024 * 1024);

    quant_all<<<30079, 256, 0, stream>>>(nodef, edgef, nodeQ, edgeQ);

    spe_fused_q<<<2048, BLOCK, 0, stream>>>(
        nodef, nodeQ, edgeQ, src_ids, dst_ids, itimes,
        s_nbr, s_eid, s_t, d_nbr, d_eid, d_t,
        tw, tb, W, bout, out);
}

// Round 13
// 220.231 us; speedup vs baseline: 1.4667x; 1.2909x over previous
//
#include <hip/hip_runtime.h>

#define ROWS  16
#define BLOCK 512
#define PAD   620   // 616 padded; 2480B row, 16B-aligned

__global__ __launch_bounds__(BLOCK) void spe_fused(
    const float* __restrict__ nodef,   // [200000,172]
    const float* __restrict__ edgef,   // [500000,172]
    const int*   __restrict__ src_ids, // [8192]
    const int*   __restrict__ dst_ids, // [8192]
    const float* __restrict__ itimes,  // [8192]
    const int*   __restrict__ s_nbr,   // [8192,32]
    const int*   __restrict__ s_eid,   // [8192,32]
    const float* __restrict__ s_t,     // [8192,32]
    const int*   __restrict__ d_nbr,
    const int*   __restrict__ d_eid,
    const float* __restrict__ d_t,
    const float* __restrict__ tw,      // [100]
    const float* __restrict__ tb,      // [100]
    const float* __restrict__ W,       // [616,172]
    const float* __restrict__ bout,    // [172]
    float*       __restrict__ out)     // [3,8192,172]
{
    __shared__ float inp[ROWS * PAD];
    __shared__ int   noff[ROWS * 32];
    __shared__ int   eoff[ROWS * 32];
    __shared__ float dtm[ROWS * 32];
    __shared__ float msk[ROWS * 32];
    __shared__ int   curoff[ROWS];
    __shared__ float twl[100], tbl[100];

    const int tid     = threadIdx.x;
    const int side    = blockIdx.x >> 9;           // 512 blocks per side
    const int rowbase = (blockIdx.x & 511) * ROWS;

    const int*   nbr  = side ? d_nbr : s_nbr;
    const int*   eidp = side ? d_eid : s_eid;
    const float* ntp  = side ? d_t   : s_t;
    const int*   nids = side ? dst_ids : src_ids;

    // ---- stage ids / dt / mask (one item per thread: 16*32 == 512) ----
    {
        int i   = tid;
        int g   = rowbase * 32 + i;
        int nid = nbr[g];
        noff[i] = nid * 172;
        eoff[i] = eidp[g] * 172;
        dtm[i]  = itimes[rowbase + (i >> 5)] - ntp[g];
        msk[i]  = (nid == 0) ? 0.f : 1.f;
    }
    if (tid < ROWS) curoff[tid] = nids[rowbase + tid] * 172;
    if (tid < 100) { twl[tid] = tw[tid]; tbl[tid] = tb[tid]; }
    __syncthreads();

    // ---- cur node copy (float4): inp[r][0:172] ----
    for (int i = tid; i < ROWS * 43; i += BLOCK) {
        int r = i / 43, c = i - r * 43;
        *(float4*)&inp[r * PAD + 4 * c] =
            *(const float4*)&nodef[curoff[r] + 4 * c];
    }

    // ---- node gather mean (float4, 8 loads in flight): inp[r][172+d] ----
    for (int i = tid; i < ROWS * 43; i += BLOCK) {
        int r = i / 43, c = i - r * 43;
        const int dd = 4 * c, rb = r * 32;
        float4 acc = {0.f, 0.f, 0.f, 0.f};
        #pragma unroll
        for (int s0 = 0; s0 < 32; s0 += 8) {
            float4 v[8];
            #pragma unroll
            for (int u = 0; u < 8; ++u)
                v[u] = *(const float4*)&nodef[noff[rb + s0 + u] + dd];
            #pragma unroll
            for (int u = 0; u < 8; ++u) {
                acc.x += v[u].x; acc.y += v[u].y;
                acc.z += v[u].z; acc.w += v[u].w;
            }
        }
        acc.x *= (1.f/32.f); acc.y *= (1.f/32.f);
        acc.z *= (1.f/32.f); acc.w *= (1.f/32.f);
        *(float4*)&inp[r * PAD + 172 + dd] = acc;
    }

    // ---- edge gather mean (float4, 8 loads in flight): inp[r][344+d] ----
    for (int i = tid; i < ROWS * 43; i += BLOCK) {
        int r = i / 43, c = i - r * 43;
        const int dd = 4 * c, rb = r * 32;
        float4 acc = {0.f, 0.f, 0.f, 0.f};
        #pragma unroll
        for (int s0 = 0; s0 < 32; s0 += 8) {
            float4 v[8];
            #pragma unroll
            for (int u = 0; u < 8; ++u)
                v[u] = *(const float4*)&edgef[eoff[rb + s0 + u] + dd];
            #pragma unroll
            for (int u = 0; u < 8; ++u) {
                acc.x += v[u].x; acc.y += v[u].y;
                acc.z += v[u].z; acc.w += v[u].w;
            }
        }
        acc.x *= (1.f/32.f); acc.y *= (1.f/32.f);
        acc.z *= (1.f/32.f); acc.w *= (1.f/32.f);
        *(float4*)&inp[r * PAD + 344 + dd] = acc;
    }

    // ---- time encoding: inp[r][516+j] ----
    for (int i = tid; i < ROWS * 100; i += BLOCK) {
        int r = i / 100, j = i - r * 100;
        const int rb = r * 32;
        float w = twl[j], b = tbl[j];
        float acc = 0.f;
        #pragma unroll
        for (int s = 0; s < 32; ++s)
            acc += msk[rb + s] * __cosf(dtm[rb + s] * w + b);
        inp[r * PAD + 516 + j] = acc * (1.f / 32.f);
    }

    // ---- dummy third output = zeros: split across ALL 1024 blocks (8 rows each) ----
    {
        const float4 z = {0.f, 0.f, 0.f, 0.f};
        const int zbase = blockIdx.x * 8;           // 1024*8 = 8192 rows
        for (int i = tid; i < 8 * 43; i += BLOCK) {
            int r = i / 43, c = i - r * 43;
            *(float4*)&out[(size_t)(2 * 8192 + zbase + r) * 172 + 4 * c] = z;
        }
    }
    __syncthreads();

    // ---- GEMM: out[16,172] = relu(inp[16,616] @ W[616,172] + b) ----
    // 344 threads = 8 row-tiles x 43 col-tiles, each thread 2 rows x 4 cols
    if (tid < 344) {
        const int ct = tid % 43, rt = tid / 43;
        const int j0 = ct * 4, r0 = rt * 2;
        float acc[2][4] = {};
        float a[2][4];
        for (int k = 0; k < 616; k += 4) {
            #pragma unroll
            for (int ri = 0; ri < 2; ++ri)
                *(float4*)&a[ri][0] = *(const float4*)&inp[(r0 + ri) * PAD + k];
            #pragma unroll
            for (int kk = 0; kk < 4; ++kk) {
                float4 wv = *(const float4*)&W[(k + kk) * 172 + j0];
                #pragma unroll
                for (int ri = 0; ri < 2; ++ri) {
                    acc[ri][0] += a[ri][kk] * wv.x;
                    acc[ri][1] += a[ri][kk] * wv.y;
                    acc[ri][2] += a[ri][kk] * wv.z;
                    acc[ri][3] += a[ri][kk] * wv.w;
                }
            }
        }
        float4 bias = *(const float4*)&bout[j0];
        #pragma unroll
        for (int ri = 0; ri < 2; ++ri) {
            int row = rowbase + r0 + ri;
            float4 v;
            v.x = fmaxf(acc[ri][0] + bias.x, 0.f);
            v.y = fmaxf(acc[ri][1] + bias.y, 0.f);
            v.z = fmaxf(acc[ri][2] + bias.z, 0.f);
            v.w = fmaxf(acc[ri][3] + bias.w, 0.f);
            *(float4*)&out[(size_t)(side * 8192 + row) * 172 + j0] = v;
        }
    }
}

extern "C" void kernel_launch(void* const* d_in, const int* in_sizes, int n_in,
                              void* d_out, int out_size, void* d_ws, size_t ws_size,
                              hipStream_t stream) {
    const float* nodef   = (const float*)d_in[0];
    const float* edgef   = (const float*)d_in[1];
    const int*   src_ids = (const int*)  d_in[2];
    const int*   dst_ids = (const int*)  d_in[3];
    const float* itimes  = (const float*)d_in[4];
    const int*   s_nbr   = (const int*)  d_in[5];
    const int*   s_eid   = (const int*)  d_in[6];
    const float* s_t     = (const float*)d_in[7];
    const int*   d_nbr   = (const int*)  d_in[8];
    const int*   d_eid   = (const int*)  d_in[9];
    const float* d_t     = (const float*)d_in[10];
    const float* tw      = (const float*)d_in[11];
    const float* tb      = (const float*)d_in[12];
    const float* W       = (const float*)d_in[13];
    const float* bout    = (const float*)d_in[14];
    float* out = (float*)d_out;

    spe_fused<<<1024, BLOCK, 0, stream>>>(
        nodef, edgef, src_ids, dst_ids, itimes,
        s_nbr, s_eid, s_t, d_nbr, d_eid, d_t,
        tw, tb, W, bout, out);
}